// Round 7
// baseline (1124.177 us; speedup 1.0000x reference)
//
#include <hip/hip_runtime.h>

// ---- problem constants ----
#define SIZE   48
#define DESIZE 44
#define PAD    3
#define BATCH  4
#define FLAT   (DESIZE*SIZE*SIZE)      // 101376
#define CVOL   216                     // 6*6*6

// stencil tile: 1 (i) x 4 (j) x 16 (k) voxels per block, 64 voxels, ALL 4 batches
#define TJ 4
#define TK 16
#define NA 6
#define NB (TJ+5)                      // 9
#define NC (TK+5)                      // 21
#define NEU_T (NA*NB*NC)               // 1134 halo elements (float4 over batches)
#define NTILE 1584                     // 44*36

// MLP1 split-K: 132*768 = 101376 -> grid 768 = exactly 3 blocks/CU (no tail round)
#define KSLICE  132
#define NSLICES (FLAT/KSLICE)          // 768

// Each warp handles a contiguous slice of the 54 float4-chunks of its lane's
// synapse row. First 7 chunks arrive via `pre` (issued BEFORE halo staging so
// their L3 latency hides under staging+barrier); the rest load here.
template <int CBASE, int CNT>
__device__ __forceinline__ void do_chunk4(const float4 pre[7],
                                          const float4* __restrict__ rp,
                                          const float4* __restrict__ neu4,
                                          int lanebase, float acc[4]) {
    constexpr int H2n = CNT - 7;          // 7 or 6
#pragma unroll
    for (int s2 = 0; s2 < 7; ++s2) {
#pragma unroll
        for (int j = 0; j < 4; ++j) {
            const int c   = (CBASE + s2) * 4 + j;
            const int off = (c / 36) * (NB * NC) + ((c % 36) / 6) * NC + (c % 6);
            const float wv = (&pre[s2].x)[j];
            const float4 n4 = neu4[lanebase + off];        // ds_read_b128
            acc[0] += wv * n4.x; acc[1] += wv * n4.y;
            acc[2] += wv * n4.z; acc[3] += wv * n4.w;
        }
    }
    float4 sr[H2n];
#pragma unroll
    for (int s2 = 0; s2 < H2n; ++s2) sr[s2] = rp[CBASE + 7 + s2];
#pragma unroll
    for (int s2 = 0; s2 < H2n; ++s2) {
#pragma unroll
        for (int j = 0; j < 4; ++j) {
            const int c   = (CBASE + 7 + s2) * 4 + j;
            const int off = (c / 36) * (NB * NC) + ((c % 36) / 6) * NC + (c % 6);
            const float wv = (&sr[s2].x)[j];
            const float4 n4 = neu4[lanebase + off];
            acc[0] += wv * n4.x; acc[1] += wv * n4.y;
            acc[2] += wv * n4.z; acc[3] += wv * n4.w;
        }
    }
}

// One block = one 64-voxel tile x ALL 4 batches. grid = 1584.
// neu carried between steps as float4[FLAT] = [idx][batch].
template <bool FIRST>
__global__ __launch_bounds__(256, 4) void k_step(const float4* __restrict__ nin4,
                                                 const float* __restrict__ vin,
                                                 const float* __restrict__ frame,
                                                 const float* __restrict__ syn,
                                                 float4* __restrict__ nout4) {
    __shared__ float4 neu4[NEU_T];            // 18144 B
    __shared__ float  part[4 * 256];          //  4096 B
    int t  = threadIdx.x;
    int r  = blockIdx.x;
    int i0 = r / 36;
    int r2 = r % 36;
    int j0 = (r2 / 3) * TJ;
    int k0 = (r2 % 3) * TK;

    // per-thread syn slice base; issue first 7 chunk-loads NOW (latency hides
    // under halo staging + barrier)
    int w = t >> 6, l = t & 63;
    int dj = l >> 4, dk = l & 15;
    int lanebase = dj * NC + dk;
    const float4* rp = (const float4*)(syn +
        (size_t)((i0 * SIZE + j0 + dj) * SIZE + k0 + dk) * CVOL);
    const int CB = (w == 0) ? 0 : (w == 1) ? 14 : (w == 2) ? 28 : 41;
    float4 pre[7];
#pragma unroll
    for (int s2 = 0; s2 < 7; ++s2) pre[s2] = rp[CB + s2];

    // stage neu halo (6x9x21), zero-padded, 1 coalesced dwordx4 per element
    for (int e = t; e < NEU_T; e += 256) {
        int a   = e / (NB * NC);
        int rem = e % (NB * NC);
        int jj  = rem / NC;
        int cc  = rem % NC;
        int gi = i0 + a - PAD;
        int gj = j0 + jj - PAD;
        int gk = k0 + cc - PAD;
        float4 vv = make_float4(0.f, 0.f, 0.f, 0.f);
        if ((unsigned)gi < DESIZE && (unsigned)gj < SIZE && (unsigned)gk < SIZE) {
            int idx = (gi * SIZE + gj) * SIZE + gk;
            if (FIRST) {
                float fr = frame[idx];
                vv.x = vin[0 * FLAT + idx] + fr;
                vv.y = vin[1 * FLAT + idx] + fr;
                vv.z = vin[2 * FLAT + idx] + fr;
                vv.w = vin[3 * FLAT + idx] + fr;
            } else {
                vv = nin4[idx];
            }
        }
        neu4[e] = vv;
    }
    __syncthreads();

    float acc[4] = {0.f, 0.f, 0.f, 0.f};
    switch (w) {
        case 0:  do_chunk4< 0, 14>(pre, rp, neu4, lanebase, acc); break;
        case 1:  do_chunk4<14, 14>(pre, rp, neu4, lanebase, acc); break;
        case 2:  do_chunk4<28, 13>(pre, rp, neu4, lanebase, acc); break;
        default: do_chunk4<41, 13>(pre, rp, neu4, lanebase, acc); break;
    }
#pragma unroll
    for (int bb = 0; bb < 4; ++bb) part[bb * 256 + t] = acc[bb];
    __syncthreads();

    // 64 finals: one voxel each, float4 over batches, coalesced store
    if (t < 64) {
        float4 o;
        o.x = part[  0 + t] + part[  0 + 64 + t] + part[  0 + 128 + t] + part[  0 + 192 + t];
        o.y = part[256 + t] + part[256 + 64 + t] + part[256 + 128 + t] + part[256 + 192 + t];
        o.z = part[512 + t] + part[512 + 64 + t] + part[512 + 128 + t] + part[512 + 192 + t];
        o.w = part[768 + t] + part[768 + 64 + t] + part[768 + 128 + t] + part[768 + 192 + t];
        o.x = fmaxf(o.x, 0.f) * 0.9f;
        o.y = fmaxf(o.y, 0.f) * 0.9f;
        o.z = fmaxf(o.z, 0.f) * 0.9f;
        o.w = fmaxf(o.w, 0.f) * 0.9f;
        int dj2 = t >> 4, dk2 = t & 15;
        nout4[(i0 * SIZE + (j0 + dj2)) * SIZE + (k0 + dk2)] = o;
    }
}

// x4 (FLAT x [4 batches]) @ W1 (FLAT x 1024), split-K. 256 thr, 4 cols/thread.
// KSLICE=132 -> 768 blocks = exactly 3/CU (no occupancy-quantization tail).
__global__ __launch_bounds__(256) void k_mlp1(const float4* __restrict__ x4,
                                              const float* __restrict__ W1,
                                              float* __restrict__ partial) {
    __shared__ float xs[KSLICE * 4];   // [kk][b] == float4 per kk
    int t = threadIdx.x;
    int s = blockIdx.x;
    int k0 = s * KSLICE;
    for (int e = t; e < KSLICE; e += 256)
        ((float4*)xs)[e] = x4[k0 + e];
    __syncthreads();
    float acc[4][4] = {};
    const float4* wp = (const float4*)(W1 + (size_t)k0 * 1024) + t;
#pragma unroll 6
    for (int kk = 0; kk < KSLICE; ++kk) {
        float4 w  = wp[(size_t)kk * 256];
        float4 xv = *(const float4*)(xs + kk * 4);
        acc[0][0] += xv.x * w.x; acc[0][1] += xv.x * w.y; acc[0][2] += xv.x * w.z; acc[0][3] += xv.x * w.w;
        acc[1][0] += xv.y * w.x; acc[1][1] += xv.y * w.y; acc[1][2] += xv.y * w.z; acc[1][3] += xv.y * w.w;
        acc[2][0] += xv.z * w.x; acc[2][1] += xv.z * w.y; acc[2][2] += xv.z * w.z; acc[2][3] += xv.z * w.w;
        acc[3][0] += xv.w * w.x; acc[3][1] += xv.w * w.y; acc[3][2] += xv.w * w.z; acc[3][3] += xv.w * w.w;
    }
#pragma unroll
    for (int b = 0; b < 4; ++b) {
        float4 o = make_float4(acc[b][0], acc[b][1], acc[b][2], acc[b][3]);
        *(float4*)(partial + (size_t)s * 4096 + b * 1024 + t * 4) = o;
    }
}

// Fused: reduce P1 over 768 slices -> h1=relu(.+b1) (in LDS) -> h1 @ W2 split-K.
// grid 32 (= K2 slices of 32), 128 thr.
__global__ __launch_bounds__(128) void k_red2(const float* __restrict__ partial,
                                              const float* __restrict__ b1,
                                              const float* __restrict__ W2,
                                              float* __restrict__ partial2) {
    __shared__ float h1s[32 * 4];      // [kk][b]
    int t  = threadIdx.x;
    int s  = blockIdx.x;
    int k0 = s * 32;
    {
        int kk = t & 31, b = t >> 5;   // lanes 0-31 consecutive floats: coalesced
        float a = 0.f;
#pragma unroll 16
        for (int sl = 0; sl < NSLICES; ++sl)
            a += partial[(size_t)sl * 4096 + b * 1024 + k0 + kk];
        h1s[kk * 4 + b] = fmaxf(a + b1[k0 + kk], 0.f);
    }
    __syncthreads();
    float acc[4] = {0.f, 0.f, 0.f, 0.f};
#pragma unroll
    for (int k2 = 0; k2 < 32; ++k2) {
        float wv  = W2[(size_t)(k0 + k2) * 128 + t];
        float4 xv = *(const float4*)(h1s + k2 * 4);
        acc[0] += xv.x * wv; acc[1] += xv.y * wv;
        acc[2] += xv.z * wv; acc[3] += xv.w * wv;
    }
#pragma unroll
    for (int bb = 0; bb < 4; ++bb) partial2[s * 512 + bb * 128 + t] = acc[bb];
}

__global__ __launch_bounds__(128) void k_mlp3(const float* __restrict__ partial2,
                                              const float* __restrict__ b2,
                                              const float* __restrict__ W3,
                                              const float* __restrict__ b3,
                                              float* __restrict__ out) {
    __shared__ float h2[512];   // [b][n2]
    int t = threadIdx.x;
    for (int e = t; e < 512; e += 128) {
        int n2 = e & 127;
        float a = b2[n2];
#pragma unroll 8
        for (int s = 0; s < 32; ++s) a += partial2[s * 512 + e];
        h2[e] = fmaxf(a, 0.f);
    }
    __syncthreads();
    if (t < 40) {
        int b = t / 10, o = t % 10;
        float a = b3[o];
        for (int k = 0; k < 128; ++k) a += h2[b * 128 + k] * W3[k * 10 + o];
        out[b * 10 + o] = a;
    }
}

extern "C" void kernel_launch(void* const* d_in, const int* in_sizes, int n_in,
                              void* d_out, int out_size, void* d_ws, size_t ws_size,
                              hipStream_t stream) {
    const float* vin   = (const float*)d_in[0];
    const float* frame = (const float*)d_in[1];
    const float* syn   = (const float*)d_in[2];
    const float* W1    = (const float*)d_in[3];
    const float* b1    = (const float*)d_in[4];
    const float* W2    = (const float*)d_in[5];
    const float* b2    = (const float*)d_in[6];
    const float* W3    = (const float*)d_in[7];
    const float* b3    = (const float*)d_in[8];
    float* out = (float*)d_out;

    float* ws = (float*)d_ws;
    float* A   = ws;                          // FLAT float4 = 405504 floats
    float* B   = A + (size_t)BATCH * FLAT;
    float* P1  = B + (size_t)BATCH * FLAT;    // 768*4096 = 3.15M floats
    float* P2  = P1 + (size_t)NSLICES * 4096; // 32*512 = 16384

    k_step<true ><<<NTILE, 256, 0, stream>>>(nullptr, vin, frame, syn, (float4*)A);
    k_step<false><<<NTILE, 256, 0, stream>>>((const float4*)A, nullptr, nullptr, syn, (float4*)B);
    k_step<false><<<NTILE, 256, 0, stream>>>((const float4*)B, nullptr, nullptr, syn, (float4*)A);
    k_step<false><<<NTILE, 256, 0, stream>>>((const float4*)A, nullptr, nullptr, syn, (float4*)B);
    k_step<false><<<NTILE, 256, 0, stream>>>((const float4*)B, nullptr, nullptr, syn, (float4*)A);

    k_mlp1<<<NSLICES, 256, 0, stream>>>((const float4*)A, W1, P1);
    k_red2<<<32, 128, 0, stream>>>(P1, b1, W2, P2);
    k_mlp3<<<1, 128, 0, stream>>>(P2, b2, W3, b3, out);
}

// Round 8
// 702.944 us; speedup vs baseline: 1.5992x; 1.5992x over previous
//
#include <hip/hip_runtime.h>

// ---- problem constants ----
#define SIZE   48
#define DESIZE 44
#define PAD    3
#define BATCH  4
#define FLAT   (DESIZE*SIZE*SIZE)      // 101376
#define CVOL   216                     // 6*6*6

// stencil tile: 1 (i) x 4 (j) x 16 (k) voxels per block, 64 voxels, ALL 4 batches
#define TJ 4
#define TK 16
#define NA 6
#define NB (TJ+5)                      // 9
#define NC (TK+5)                      // 21
#define NEU_T (NA*NB*NC)               // 1134 halo elements (float4 over batches)
#define NTILE 1584                     // 44*36

// MLP1 split-K: 132*768 = 101376 -> grid 768 = exactly 3 blocks/CU (no tail round)
#define KSLICE  132
#define NSLICES (FLAT/KSLICE)          // 768

// Each warp handles a contiguous slice of the 54 float4-chunks of its lane's
// synapse row, held in VGPRs (rows are 864B contiguous; L1 captures the stream).
// NOTE (R7 lesson): do NOT hoist these loads before the staging loop — the
// 28 live VGPRs across the register-pressured staging phase cause spills
// under the (256,4) cap and serialize staging behind the scattered syn loads.
template <int CBASE, int CNT>
__device__ __forceinline__ void do_chunk4(const float4* __restrict__ rp,
                                          const float4* __restrict__ neu4,
                                          int lanebase, float acc[4]) {
    constexpr int H1n = (CNT + 1) / 2;
    constexpr int H2n = CNT - H1n;
    {
        float4 sr[H1n];
#pragma unroll
        for (int s2 = 0; s2 < H1n; ++s2) sr[s2] = rp[CBASE + s2];
#pragma unroll
        for (int s2 = 0; s2 < H1n; ++s2) {
#pragma unroll
            for (int j = 0; j < 4; ++j) {
                const int c   = (CBASE + s2) * 4 + j;
                const int off = (c / 36) * (NB * NC) + ((c % 36) / 6) * NC + (c % 6);
                const float wv = (&sr[s2].x)[j];
                const float4 n4 = neu4[lanebase + off];        // ds_read_b128
                acc[0] += wv * n4.x; acc[1] += wv * n4.y;
                acc[2] += wv * n4.z; acc[3] += wv * n4.w;
            }
        }
    }
    {
        float4 sr[H2n];
#pragma unroll
        for (int s2 = 0; s2 < H2n; ++s2) sr[s2] = rp[CBASE + H1n + s2];
#pragma unroll
        for (int s2 = 0; s2 < H2n; ++s2) {
#pragma unroll
            for (int j = 0; j < 4; ++j) {
                const int c   = (CBASE + H1n + s2) * 4 + j;
                const int off = (c / 36) * (NB * NC) + ((c % 36) / 6) * NC + (c % 6);
                const float wv = (&sr[s2].x)[j];
                const float4 n4 = neu4[lanebase + off];
                acc[0] += wv * n4.x; acc[1] += wv * n4.y;
                acc[2] += wv * n4.z; acc[3] += wv * n4.w;
            }
        }
    }
}

// One block = one 64-voxel tile x ALL 4 batches. grid = 1584.
// neu carried between steps as float4[FLAT] = [idx][batch].
template <bool FIRST>
__global__ __launch_bounds__(256, 4) void k_step(const float4* __restrict__ nin4,
                                                 const float* __restrict__ vin,
                                                 const float* __restrict__ frame,
                                                 const float* __restrict__ syn,
                                                 float4* __restrict__ nout4) {
    __shared__ float4 neu4[NEU_T];            // 18144 B
    __shared__ float  part[4 * 256];          //  4096 B
    int t  = threadIdx.x;
    int r  = blockIdx.x;
    int i0 = r / 36;
    int r2 = r % 36;
    int j0 = (r2 / 3) * TJ;
    int k0 = (r2 % 3) * TK;

    // stage neu halo (6x9x21), zero-padded, 1 coalesced dwordx4 per element
    for (int e = t; e < NEU_T; e += 256) {
        int a   = e / (NB * NC);
        int rem = e % (NB * NC);
        int jj  = rem / NC;
        int cc  = rem % NC;
        int gi = i0 + a - PAD;
        int gj = j0 + jj - PAD;
        int gk = k0 + cc - PAD;
        float4 vv = make_float4(0.f, 0.f, 0.f, 0.f);
        if ((unsigned)gi < DESIZE && (unsigned)gj < SIZE && (unsigned)gk < SIZE) {
            int idx = (gi * SIZE + gj) * SIZE + gk;
            if (FIRST) {
                float fr = frame[idx];
                vv.x = vin[0 * FLAT + idx] + fr;
                vv.y = vin[1 * FLAT + idx] + fr;
                vv.z = vin[2 * FLAT + idx] + fr;
                vv.w = vin[3 * FLAT + idx] + fr;
            } else {
                vv = nin4[idx];
            }
        }
        neu4[e] = vv;
    }
    __syncthreads();

    int w = t >> 6, l = t & 63;
    int dj = l >> 4, dk = l & 15;
    int lanebase = dj * NC + dk;
    const float4* rp = (const float4*)(syn +
        (size_t)((i0 * SIZE + j0 + dj) * SIZE + k0 + dk) * CVOL);

    float acc[4] = {0.f, 0.f, 0.f, 0.f};
    switch (w) {
        case 0:  do_chunk4< 0, 14>(rp, neu4, lanebase, acc); break;
        case 1:  do_chunk4<14, 14>(rp, neu4, lanebase, acc); break;
        case 2:  do_chunk4<28, 13>(rp, neu4, lanebase, acc); break;
        default: do_chunk4<41, 13>(rp, neu4, lanebase, acc); break;
    }
#pragma unroll
    for (int bb = 0; bb < 4; ++bb) part[bb * 256 + t] = acc[bb];
    __syncthreads();

    // 64 finals: one voxel each, float4 over batches, coalesced store
    if (t < 64) {
        float4 o;
        o.x = part[  0 + t] + part[  0 + 64 + t] + part[  0 + 128 + t] + part[  0 + 192 + t];
        o.y = part[256 + t] + part[256 + 64 + t] + part[256 + 128 + t] + part[256 + 192 + t];
        o.z = part[512 + t] + part[512 + 64 + t] + part[512 + 128 + t] + part[512 + 192 + t];
        o.w = part[768 + t] + part[768 + 64 + t] + part[768 + 128 + t] + part[768 + 192 + t];
        o.x = fmaxf(o.x, 0.f) * 0.9f;
        o.y = fmaxf(o.y, 0.f) * 0.9f;
        o.z = fmaxf(o.z, 0.f) * 0.9f;
        o.w = fmaxf(o.w, 0.f) * 0.9f;
        int dj2 = t >> 4, dk2 = t & 15;
        nout4[(i0 * SIZE + (j0 + dj2)) * SIZE + (k0 + dk2)] = o;
    }
}

// x4 (FLAT x [4 batches]) @ W1 (FLAT x 1024), split-K. 256 thr, 4 cols/thread.
// KSLICE=132 -> 768 blocks = exactly 3/CU (no occupancy-quantization tail).
__global__ __launch_bounds__(256) void k_mlp1(const float4* __restrict__ x4,
                                              const float* __restrict__ W1,
                                              float* __restrict__ partial) {
    __shared__ float xs[KSLICE * 4];   // [kk][b] == float4 per kk
    int t = threadIdx.x;
    int s = blockIdx.x;
    int k0 = s * KSLICE;
    for (int e = t; e < KSLICE; e += 256)
        ((float4*)xs)[e] = x4[k0 + e];
    __syncthreads();
    float acc[4][4] = {};
    const float4* wp = (const float4*)(W1 + (size_t)k0 * 1024) + t;
#pragma unroll 6
    for (int kk = 0; kk < KSLICE; ++kk) {
        float4 w  = wp[(size_t)kk * 256];
        float4 xv = *(const float4*)(xs + kk * 4);
        acc[0][0] += xv.x * w.x; acc[0][1] += xv.x * w.y; acc[0][2] += xv.x * w.z; acc[0][3] += xv.x * w.w;
        acc[1][0] += xv.y * w.x; acc[1][1] += xv.y * w.y; acc[1][2] += xv.y * w.z; acc[1][3] += xv.y * w.w;
        acc[2][0] += xv.z * w.x; acc[2][1] += xv.z * w.y; acc[2][2] += xv.z * w.z; acc[2][3] += xv.z * w.w;
        acc[3][0] += xv.w * w.x; acc[3][1] += xv.w * w.y; acc[3][2] += xv.w * w.z; acc[3][3] += xv.w * w.w;
    }
#pragma unroll
    for (int b = 0; b < 4; ++b) {
        float4 o = make_float4(acc[b][0], acc[b][1], acc[b][2], acc[b][3]);
        *(float4*)(partial + (size_t)s * 4096 + b * 1024 + t * 4) = o;
    }
}

// reduce NSLICES partials -> h1 = relu(sum + b1). 256 blocks x 256 thr.
__global__ __launch_bounds__(256) void k_reduce1(const float* __restrict__ partial,
                                                 const float* __restrict__ b1,
                                                 float* __restrict__ h1) {
    __shared__ float red[16][17];
    int t = threadIdx.x;
    int e0 = blockIdx.x * 16;
    int eo = t & 15, sl = t >> 4;
    float acc = 0.f;
    for (int it = 0; it < NSLICES / 16; ++it) {
        int s = sl + 16 * it;
        acc += partial[(size_t)s * 4096 + e0 + eo];
    }
    red[sl][eo] = acc;
    __syncthreads();
    if (t < 16) {
        float a = 0.f;
#pragma unroll
        for (int rr = 0; rr < 16; ++rr) a += red[rr][t];
        int e = e0 + t;
        h1[e] = fmaxf(a + b1[e & 1023], 0.f);
    }
}

// h1 (4x1024) @ W2 (1024x128), split-K 32 x 2 col-chunks, 64 thr. grid=64.
__global__ __launch_bounds__(64) void k_mlp2(const float* __restrict__ h1,
                                             const float* __restrict__ W2,
                                             float* __restrict__ partial2) {
    __shared__ float xs[32 * 4];
    int t = threadIdx.x;
    int bid = blockIdx.x;
    int s = bid >> 1, ch = bid & 1;
    int k0 = s * 32;
    for (int e = t; e < 128; e += 64) {
        int kk = e >> 2, b = e & 3;
        xs[e] = h1[b * 1024 + k0 + kk];
    }
    __syncthreads();
    float acc[4] = {0.f, 0.f, 0.f, 0.f};
    int n2 = ch * 64 + t;
#pragma unroll
    for (int kk = 0; kk < 32; ++kk) {
        float w = W2[(size_t)(k0 + kk) * 128 + n2];
        float4 xv = *(const float4*)(xs + kk * 4);
        acc[0] += xv.x * w; acc[1] += xv.y * w; acc[2] += xv.z * w; acc[3] += xv.w * w;
    }
#pragma unroll
    for (int b = 0; b < 4; ++b) partial2[s * 512 + b * 128 + n2] = acc[b];
}

__global__ __launch_bounds__(128) void k_mlp3(const float* __restrict__ partial2,
                                              const float* __restrict__ b2,
                                              const float* __restrict__ W3,
                                              const float* __restrict__ b3,
                                              float* __restrict__ out) {
    __shared__ float h2[512];   // [b][n2]
    int t = threadIdx.x;
    for (int e = t; e < 512; e += 128) {
        int n2 = e & 127;
        float a = b2[n2];
#pragma unroll 8
        for (int s = 0; s < 32; ++s) a += partial2[s * 512 + e];
        h2[e] = fmaxf(a, 0.f);
    }
    __syncthreads();
    if (t < 40) {
        int b = t / 10, o = t % 10;
        float a = b3[o];
        for (int k = 0; k < 128; ++k) a += h2[b * 128 + k] * W3[k * 10 + o];
        out[b * 10 + o] = a;
    }
}

extern "C" void kernel_launch(void* const* d_in, const int* in_sizes, int n_in,
                              void* d_out, int out_size, void* d_ws, size_t ws_size,
                              hipStream_t stream) {
    const float* vin   = (const float*)d_in[0];
    const float* frame = (const float*)d_in[1];
    const float* syn   = (const float*)d_in[2];
    const float* W1    = (const float*)d_in[3];
    const float* b1    = (const float*)d_in[4];
    const float* W2    = (const float*)d_in[5];
    const float* b2    = (const float*)d_in[6];
    const float* W3    = (const float*)d_in[7];
    const float* b3    = (const float*)d_in[8];
    float* out = (float*)d_out;

    float* ws = (float*)d_ws;
    float* A   = ws;                          // FLAT float4 = 405504 floats
    float* B   = A + (size_t)BATCH * FLAT;
    float* P1  = B + (size_t)BATCH * FLAT;    // 768*4096 = 3.15M floats
    float* H1  = P1 + (size_t)NSLICES * 4096; // 4096
    float* P2  = H1 + 4096;                   // 32*512 = 16384

    k_step<true ><<<NTILE, 256, 0, stream>>>(nullptr, vin, frame, syn, (float4*)A);
    k_step<false><<<NTILE, 256, 0, stream>>>((const float4*)A, nullptr, nullptr, syn, (float4*)B);
    k_step<false><<<NTILE, 256, 0, stream>>>((const float4*)B, nullptr, nullptr, syn, (float4*)A);
    k_step<false><<<NTILE, 256, 0, stream>>>((const float4*)A, nullptr, nullptr, syn, (float4*)B);
    k_step<false><<<NTILE, 256, 0, stream>>>((const float4*)B, nullptr, nullptr, syn, (float4*)A);

    k_mlp1<<<NSLICES, 256, 0, stream>>>((const float4*)A, W1, P1);
    k_reduce1<<<256, 256, 0, stream>>>(P1, b1, H1);
    k_mlp2<<<64, 64, 0, stream>>>(H1, W2, P2);
    k_mlp3<<<1, 128, 0, stream>>>(P2, b2, W3, b3, out);
}